// Round 1
// baseline (387.042 us; speedup 1.0000x reference)
//
#include <hip/hip_runtime.h>
#include <cstddef>

// Dims (fixed by problem)
// B=4, S=512, N*DIM=128, D_MODEL=1024, D_STATE=64
constexpr int ROWS = 2048;   // B*S

// ---------------- K0: rearrange W_xp (1024x129) -> wBC (1024x128) + wd (1024)
__global__ __launch_bounds__(256)
void k0_rearrange(const float* __restrict__ Wxp,
                  float* __restrict__ wBC, float* __restrict__ wd) {
  int idx = blockIdx.x * 256 + threadIdx.x;
  if (idx >= 1024 * 129) return;
  int k = idx / 129;
  int c = idx - k * 129;
  float v = Wxp[idx];
  if (c == 0) wd[k] = v;
  else        wBC[k * 128 + (c - 1)] = v;
}

// ---------------- Generic tiled fp32 GEMM: 64x64 tile, TK=32, 4x4 micro ----
// A: MxK row-major, Bm: KxN row-major. SPLIT: write partial to C + z*M*N,
// no bias. !SPLIT: write C with optional bias.
template<bool SPLIT>
__global__ __launch_bounds__(256)
void gemm_f32(const float* __restrict__ A, const float* __restrict__ Bm,
              const float* __restrict__ bias, float* __restrict__ C,
              int M, int N, int K, int kchunk) {
  __shared__ float As[32][68];   // [k][m], pad 4 keeps 16B row alignment
  __shared__ float Bs[32][68];   // [k][n]
  const int t  = threadIdx.x;
  const int n0 = blockIdx.x * 64;
  const int m0 = blockIdx.y * 64;
  int k0 = 0, kend = K;
  if (SPLIT) { k0 = blockIdx.z * kchunk; kend = k0 + kchunk; }
  const int tx = t & 15, ty = t >> 4;
  const int arow = t >> 3, acol = (t & 7) << 2;   // A tile: 32 rows x 32 k (x2 halves)
  const int brow = t >> 4, bcol = (t & 15) << 2;  // B tile: 16 k x 64 n (x2 halves)
  float acc[4][4] = {{0.f}};

  for (int kt = k0; kt < kend; kt += 32) {
    float4 a0 = *(const float4*)&A[(size_t)(m0 + arow)      * K + kt + acol];
    float4 a1 = *(const float4*)&A[(size_t)(m0 + arow + 32) * K + kt + acol];
    float4 b0 = *(const float4*)&Bm[(size_t)(kt + brow)      * N + n0 + bcol];
    float4 b1 = *(const float4*)&Bm[(size_t)(kt + brow + 16) * N + n0 + bcol];
    __syncthreads();
    As[acol + 0][arow] = a0.x; As[acol + 1][arow] = a0.y;
    As[acol + 2][arow] = a0.z; As[acol + 3][arow] = a0.w;
    As[acol + 0][arow + 32] = a1.x; As[acol + 1][arow + 32] = a1.y;
    As[acol + 2][arow + 32] = a1.z; As[acol + 3][arow + 32] = a1.w;
    *(float4*)&Bs[brow][bcol]      = b0;
    *(float4*)&Bs[brow + 16][bcol] = b1;
    __syncthreads();
    #pragma unroll
    for (int k = 0; k < 32; ++k) {
      float4 av = *(const float4*)&As[k][ty << 2];
      float4 bv = *(const float4*)&Bs[k][tx << 2];
      float a_[4] = {av.x, av.y, av.z, av.w};
      float b_[4] = {bv.x, bv.y, bv.z, bv.w};
      #pragma unroll
      for (int i = 0; i < 4; ++i)
        #pragma unroll
        for (int j = 0; j < 4; ++j)
          acc[i][j] = fmaf(a_[i], b_[j], acc[i][j]);
    }
  }

  float* Cp = C;
  if (SPLIT) Cp += (size_t)blockIdx.z * (size_t)M * N;
  #pragma unroll
  for (int i = 0; i < 4; ++i) {
    int row = m0 + (ty << 2) + i;
    float4 v = make_float4(acc[i][0], acc[i][1], acc[i][2], acc[i][3]);
    if (!SPLIT && bias) {
      float4 bb = *(const float4*)&bias[n0 + (tx << 2)];
      v.x += bb.x; v.y += bb.y; v.z += bb.z; v.w += bb.w;
    }
    *(float4*)&Cp[(size_t)row * N + n0 + (tx << 2)] = v;
  }
}

// ---------------- K2d: delta GEMV: d_raw[row] = u[row,:] . wd ----------------
__global__ __launch_bounds__(256)
void k2d_gemv(const float* __restrict__ u, const float* __restrict__ wd,
              float* __restrict__ d_raw) {
  int t = threadIdx.x, lane = t & 63, wv = t >> 6;
  int row = blockIdx.x * 4 + wv;
  const float* up = u + (size_t)row * 1024;
  float acc = 0.f;
  #pragma unroll
  for (int i = 0; i < 16; ++i)
    acc = fmaf(up[lane + i * 64], wd[lane + i * 64], acc);
  #pragma unroll
  for (int o = 32; o; o >>= 1) acc += __shfl_xor(acc, o, 64);
  if (lane == 0) d_raw[row] = acc;
}

// ---------------- K2e: reduce split-K partials + build abc -------------------
// abc[row][0:64]=A_bar, [64:128]=B_bar, [128:192]=C
__global__ __launch_bounds__(256)
void k2e_epilogue(const float* __restrict__ part, const float* __restrict__ d_raw,
                  const float* __restrict__ bxp, const float* __restrict__ A,
                  float* __restrict__ abc) {
  int gid = blockIdx.x * 256 + threadIdx.x;  // 0..131071
  int row = gid >> 6, d = gid & 63;
  const size_t PN = (size_t)ROWS * 128;
  float sb = 0.f, sc = 0.f;
  #pragma unroll
  for (int z = 0; z < 4; ++z) {
    sb += part[z * PN + (size_t)row * 128 + d];
    sc += part[z * PN + (size_t)row * 128 + 64 + d];
  }
  sb += bxp[1 + d];
  sc += bxp[65 + d];
  float x = d_raw[row] + bxp[0];
  float sp = (x > 15.f) ? x : log1pf(__expf(x));
  float delta = 0.01f * sp;
  float* o = abc + (size_t)row * 192;
  o[d]       = __expf(delta * A[d]);
  o[64 + d]  = delta * sb;
  o[128 + d] = sc;
}

// ---------------- K3: the sequential scan -----------------------------------
// Wave = 2 m-streams for one b; lane = d. Block = 4 waves (8 m's), same b.
// abc rows staged in LDS 32 steps at a time (amortizes L2 broadcast traffic).
__global__ __launch_bounds__(256)
void scan_kernel(const float* __restrict__ u, const float* __restrict__ abc,
                 const float* __restrict__ Dp, float* __restrict__ y) {
  __shared__ __align__(16) float sbuf[32 * 192];  // 24 KB
  const int t = threadIdx.x;
  const int lane = t & 63;
  const int wv = t >> 6;             // 0..3
  const int b  = blockIdx.x >> 7;    // 512 blocks = 4 b * 128 mgroups
  const int mg = blockIdx.x & 127;
  const int m0 = mg * 8 + wv * 2;
  const float dp0 = Dp[m0], dp1 = Dp[m0 + 1];
  const float* ub = u + ((size_t)b * 512) * 1024 + m0;
  float*       yb = y + ((size_t)b * 512) * 1024 + m0;
  const float* ab = abc + (size_t)b * 512 * 192;
  float h0 = 0.f, h1 = 0.f;

  for (int c0 = 0; c0 < 512; c0 += 32) {
    __syncthreads();
    const float4* src = (const float4*)(ab + (size_t)c0 * 192);
    #pragma unroll
    for (int i = 0; i < 6; ++i)
      ((float4*)sbuf)[t + i * 256] = src[t + i * 256];
    __syncthreads();
    for (int s = 0; s < 32; ++s) {
      const int row = c0 + s;
      const float* L = sbuf + s * 192;
      float a  = L[lane];
      float bb = L[64 + lane];
      float cc = L[128 + lane];
      float2 ut = *(const float2*)(ub + (size_t)row * 1024);
      h0 = fmaf(h0, a, bb * ut.x);
      h1 = fmaf(h1, a, bb * ut.y);
      float p0 = h0 * cc, p1 = h1 * cc;
      #pragma unroll
      for (int o = 32; o; o >>= 1) {
        p0 += __shfl_xor(p0, o, 64);
        p1 += __shfl_xor(p1, o, 64);
      }
      if (lane == 0) {
        float2 o2 = make_float2(p0 + ut.x * dp0, p1 + ut.y * dp1);
        *(float2*)(yb + (size_t)row * 1024) = o2;
      }
    }
  }
}

// ---------------- K4a: LayerNorm over 1024, write yn -------------------------
__global__ __launch_bounds__(256)
void k4a_ln(const float* __restrict__ y, const float* __restrict__ gamma,
            const float* __restrict__ beta, float* __restrict__ yn) {
  __shared__ float red[8];
  int t = threadIdx.x, lane = t & 63, wv = t >> 6;
  int row = blockIdx.x;
  float4 v = *(const float4*)&y[(size_t)row * 1024 + t * 4];
  float s1 = v.x + v.y + v.z + v.w;
  float s2 = v.x * v.x + v.y * v.y + v.z * v.z + v.w * v.w;
  #pragma unroll
  for (int o = 32; o; o >>= 1) {
    s1 += __shfl_xor(s1, o, 64);
    s2 += __shfl_xor(s2, o, 64);
  }
  if (lane == 0) { red[wv] = s1; red[4 + wv] = s2; }
  __syncthreads();
  float S1 = red[0] + red[1] + red[2] + red[3];
  float S2 = red[4] + red[5] + red[6] + red[7];
  float mean = S1 * (1.f / 1024.f);
  float var  = S2 * (1.f / 1024.f) - mean * mean;
  float rstd = rsqrtf(var + 1e-5f);
  float4 g  = *(const float4*)&gamma[t * 4];
  float4 be = *(const float4*)&beta[t * 4];
  float4 o;
  o.x = (v.x - mean) * rstd * g.x + be.x;
  o.y = (v.y - mean) * rstd * g.y + be.y;
  o.z = (v.z - mean) * rstd * g.z + be.z;
  o.w = (v.w - mean) * rstd * g.w + be.w;
  *(float4*)&yn[(size_t)row * 1024 + t * 4] = o;
}

// ---------------- K4c: reduce split-K partials + b_out -> out ----------------
__global__ __launch_bounds__(256)
void k4c_out(const float* __restrict__ part, const float* __restrict__ bout,
             float* __restrict__ out) {
  int g4 = blockIdx.x * 256 + threadIdx.x;   // float4 index, 0..65535
  size_t idx = (size_t)g4 * 4;
  const size_t PN = (size_t)ROWS * 128;
  float4 s = *(const float4*)&part[idx];
  #pragma unroll
  for (int z = 1; z < 4; ++z) {
    float4 p = *(const float4*)&part[z * PN + idx];
    s.x += p.x; s.y += p.y; s.z += p.z; s.w += p.w;
  }
  float4 bb = *(const float4*)&bout[idx & 127];
  s.x += bb.x; s.y += bb.y; s.z += bb.z; s.w += bb.w;
  *(float4*)&out[idx] = s;
}

extern "C" void kernel_launch(void* const* d_in, const int* in_sizes, int n_in,
                              void* d_out, int out_size, void* d_ws, size_t ws_size,
                              hipStream_t stream) {
  const float* x     = (const float*)d_in[0];
  const float* W_emb = (const float*)d_in[1];
  const float* b_emb = (const float*)d_in[2];
  const float* W_xp  = (const float*)d_in[3];
  const float* b_xp  = (const float*)d_in[4];
  const float* A     = (const float*)d_in[5];
  const float* Dp    = (const float*)d_in[6];
  const float* gamma = (const float*)d_in[7];
  const float* beta  = (const float*)d_in[8];
  const float* W_out = (const float*)d_in[9];
  const float* b_out = (const float*)d_in[10];
  float* out = (float*)d_out;
  float* ws  = (float*)d_ws;

  // ws layout (floats); total ~23.1 MB
  float* u    = ws;                 // 2,097,152  (reused as yn after scan)
  float* abc  = ws + 2097152;       //   393,216
  float* y    = ws + 2490368;       // 2,097,152
  float* wBC  = ws + 4587520;       //   131,072
  float* wd   = ws + 4718592;       //     1,024
  float* dr   = ws + 4719616;       //     2,048
  float* part = ws + 4721664;       // 1,048,576 (shared by G2 and G4)
  float* yn   = u;

  // K0: split W_xp into delta-col + BC cols
  k0_rearrange<<<(1024 * 129 + 255) / 256, 256, 0, stream>>>(W_xp, wBC, wd);
  // G1: u = x @ W_emb + b_emb   (M=2048, N=1024, K=128)
  gemm_f32<false><<<dim3(16, 32, 1), 256, 0, stream>>>(x, W_emb, b_emb, u,
                                                       2048, 1024, 128, 0);
  // delta GEMV
  k2d_gemv<<<512, 256, 0, stream>>>(u, wd, dr);
  // G2: selBC partials (M=2048, N=128, K=1024, split-K=4)
  gemm_f32<true><<<dim3(2, 32, 4), 256, 0, stream>>>(u, wBC, nullptr, part,
                                                     2048, 128, 1024, 256);
  // epilogue: bias + softplus + A_bar/B_bar/C packing
  k2e_epilogue<<<512, 256, 0, stream>>>(part, dr, b_xp, A, abc);
  // K3: sequential scan -> y
  scan_kernel<<<512, 256, 0, stream>>>(u, abc, Dp, y);
  // K4a: LayerNorm -> yn (reuses u's buffer)
  k4a_ln<<<2048, 256, 0, stream>>>(y, gamma, beta, yn);
  // G4: out partials (M=2048, N=128, K=1024, split-K=4)
  gemm_f32<true><<<dim3(2, 32, 4), 256, 0, stream>>>(yn, W_out, nullptr, part,
                                                     2048, 128, 1024, 256);
  // K4c: reduce + b_out
  k4c_out<<<256, 256, 0, stream>>>(part, b_out, out);
}

// Round 2
// 180.144 us; speedup vs baseline: 2.1485x; 2.1485x over previous
//
#include <hip/hip_runtime.h>
#include <cstddef>

// Dims (fixed by problem)
// B=4, S=512, N*DIM=128, D_MODEL=1024, D_STATE=64
constexpr int ROWS = 2048;   // B*S
constexpr int NTC  = 16;     // time chunks
constexpr int CL   = 32;     // chunk length (NTC*CL == 512)

// ---------------- K0: rearrange W_xp (1024x129) -> wBC (1024x128) + wd (1024)
__global__ __launch_bounds__(256)
void k0_rearrange(const float* __restrict__ Wxp,
                  float* __restrict__ wBC, float* __restrict__ wd) {
  int idx = blockIdx.x * 256 + threadIdx.x;
  if (idx >= 1024 * 129) return;
  int k = idx / 129;
  int c = idx - k * 129;
  float v = Wxp[idx];
  if (c == 0) wd[k] = v;
  else        wBC[k * 128 + (c - 1)] = v;
}

// ---------------- Generic tiled fp32 GEMM: 64x64 tile, TK=32, 4x4 micro ----
template<bool SPLIT>
__global__ __launch_bounds__(256)
void gemm_f32(const float* __restrict__ A, const float* __restrict__ Bm,
              const float* __restrict__ bias, float* __restrict__ C,
              int M, int N, int K, int kchunk) {
  __shared__ float As[32][68];
  __shared__ float Bs[32][68];
  const int t  = threadIdx.x;
  const int n0 = blockIdx.x * 64;
  const int m0 = blockIdx.y * 64;
  int k0 = 0, kend = K;
  if (SPLIT) { k0 = blockIdx.z * kchunk; kend = k0 + kchunk; }
  const int tx = t & 15, ty = t >> 4;
  const int arow = t >> 3, acol = (t & 7) << 2;
  const int brow = t >> 4, bcol = (t & 15) << 2;
  float acc[4][4] = {{0.f}};

  for (int kt = k0; kt < kend; kt += 32) {
    float4 a0 = *(const float4*)&A[(size_t)(m0 + arow)      * K + kt + acol];
    float4 a1 = *(const float4*)&A[(size_t)(m0 + arow + 32) * K + kt + acol];
    float4 b0 = *(const float4*)&Bm[(size_t)(kt + brow)      * N + n0 + bcol];
    float4 b1 = *(const float4*)&Bm[(size_t)(kt + brow + 16) * N + n0 + bcol];
    __syncthreads();
    As[acol + 0][arow] = a0.x; As[acol + 1][arow] = a0.y;
    As[acol + 2][arow] = a0.z; As[acol + 3][arow] = a0.w;
    As[acol + 0][arow + 32] = a1.x; As[acol + 1][arow + 32] = a1.y;
    As[acol + 2][arow + 32] = a1.z; As[acol + 3][arow + 32] = a1.w;
    *(float4*)&Bs[brow][bcol]      = b0;
    *(float4*)&Bs[brow + 16][bcol] = b1;
    __syncthreads();
    #pragma unroll
    for (int k = 0; k < 32; ++k) {
      float4 av = *(const float4*)&As[k][ty << 2];
      float4 bv = *(const float4*)&Bs[k][tx << 2];
      float a_[4] = {av.x, av.y, av.z, av.w};
      float b_[4] = {bv.x, bv.y, bv.z, bv.w};
      #pragma unroll
      for (int i = 0; i < 4; ++i)
        #pragma unroll
        for (int j = 0; j < 4; ++j)
          acc[i][j] = fmaf(a_[i], b_[j], acc[i][j]);
    }
  }

  float* Cp = C;
  if (SPLIT) Cp += (size_t)blockIdx.z * (size_t)M * N;
  #pragma unroll
  for (int i = 0; i < 4; ++i) {
    int row = m0 + (ty << 2) + i;
    float4 v = make_float4(acc[i][0], acc[i][1], acc[i][2], acc[i][3]);
    if (!SPLIT && bias) {
      float4 bb = *(const float4*)&bias[n0 + (tx << 2)];
      v.x += bb.x; v.y += bb.y; v.z += bb.z; v.w += bb.w;
    }
    *(float4*)&Cp[(size_t)row * N + n0 + (tx << 2)] = v;
  }
}

// ---------------- K2d: delta GEMV: d_raw[row] = u[row,:] . wd ----------------
__global__ __launch_bounds__(256)
void k2d_gemv(const float* __restrict__ u, const float* __restrict__ wd,
              float* __restrict__ d_raw) {
  int t = threadIdx.x, lane = t & 63, wv = t >> 6;
  int row = blockIdx.x * 4 + wv;
  const float* up = u + (size_t)row * 1024;
  float acc = 0.f;
  #pragma unroll
  for (int i = 0; i < 16; ++i)
    acc = fmaf(up[lane + i * 64], wd[lane + i * 64], acc);
  #pragma unroll
  for (int o = 32; o; o >>= 1) acc += __shfl_xor(acc, o, 64);
  if (lane == 0) d_raw[row] = acc;
}

// ---------------- K2e: reduce split-K partials + build abc -------------------
// abc[row][0:64]=A_bar, [64:128]=B_bar, [128:192]=C
__global__ __launch_bounds__(256)
void k2e_epilogue(const float* __restrict__ part, const float* __restrict__ d_raw,
                  const float* __restrict__ bxp, const float* __restrict__ A,
                  float* __restrict__ abc) {
  int gid = blockIdx.x * 256 + threadIdx.x;  // 0..131071
  int row = gid >> 6, d = gid & 63;
  const size_t PN = (size_t)ROWS * 128;
  float sb = 0.f, sc = 0.f;
  #pragma unroll
  for (int z = 0; z < 4; ++z) {
    sb += part[z * PN + (size_t)row * 128 + d];
    sc += part[z * PN + (size_t)row * 128 + 64 + d];
  }
  sb += bxp[1 + d];
  sc += bxp[65 + d];
  float x = d_raw[row] + bxp[0];
  float sp = (x > 15.f) ? x : log1pf(__expf(x));
  float delta = 0.01f * sp;
  float* o = abc + (size_t)row * 192;
  o[d]       = __expf(delta * A[d]);
  o[64 + d]  = delta * sb;
  o[128 + d] = sc;
}

// ============================================================================
// Chunked scan, 3 phases. lane = m (64 m's/wave), all 64 d in registers.
// No cross-lane ops anywhere in the hot loop.
// cst layout: [b][tc<15][d][1024m] ; Ach layout: [b][tc<15][d]
// ============================================================================

// ---- S1: per-chunk summary: h-from-zero over 32 steps (+ per-d a-product) --
__global__ __launch_bounds__(256)
void scan_sum(const float* __restrict__ u, const float* __restrict__ abc,
              float* __restrict__ cst, float* __restrict__ Ach) {
  __shared__ __align__(16) float sbuf[CL * 192];  // 24 KB
  const int t = threadIdx.x, lane = t & 63, w = t >> 6;
  const int tc = blockIdx.x % 15;
  const int mg = (blockIdx.x / 15) & 3;
  const int b  = blockIdx.x / 60;
  const int r0 = b * 512 + tc * CL;

  const float4* src = (const float4*)(abc + (size_t)r0 * 192);
  #pragma unroll
  for (int i = 0; i < 6; ++i)
    ((float4*)sbuf)[t + i * 256] = src[t + i * 256];
  __syncthreads();

  const int m = (mg * 4 + w) * 64 + lane;
  const float* ub = u + (size_t)r0 * 1024 + m;
  const bool doAp = (mg == 0 && w == 0);

  float2 h[32];
  float2 ap[32];
  #pragma unroll
  for (int j = 0; j < 32; ++j) { h[j] = make_float2(0.f, 0.f); ap[j] = make_float2(1.f, 1.f); }

  float u0 = ub[0];
  float u1 = ub[1024];
  for (int s = 0; s < CL; ++s) {
    int sn = (s < CL - 3) ? s + 2 : CL - 1;
    float u2 = ub[(size_t)sn * 1024];
    const float* L = sbuf + s * 192;
    #pragma unroll
    for (int jj = 0; jj < 16; ++jj) {
      float4 a4 = *(const float4*)&L[4 * jj];
      float4 b4 = *(const float4*)&L[64 + 4 * jj];
      h[2 * jj].x     = fmaf(h[2 * jj].x,     a4.x, b4.x * u0);
      h[2 * jj].y     = fmaf(h[2 * jj].y,     a4.y, b4.y * u0);
      h[2 * jj + 1].x = fmaf(h[2 * jj + 1].x, a4.z, b4.z * u0);
      h[2 * jj + 1].y = fmaf(h[2 * jj + 1].y, a4.w, b4.w * u0);
    }
    if (doAp) {
      #pragma unroll
      for (int jj = 0; jj < 16; ++jj) {
        float4 a4 = *(const float4*)&L[4 * jj];
        ap[2 * jj].x     *= a4.x;
        ap[2 * jj].y     *= a4.y;
        ap[2 * jj + 1].x *= a4.z;
        ap[2 * jj + 1].y *= a4.w;
      }
    }
    u0 = u1; u1 = u2;
  }

  size_t cbase = (((size_t)b * 15 + tc) * 64) * 1024 + m;
  #pragma unroll
  for (int j = 0; j < 32; ++j) {
    cst[cbase + (size_t)(2 * j)     * 1024] = h[j].x;
    cst[cbase + (size_t)(2 * j + 1) * 1024] = h[j].y;
  }
  if (doAp && lane == 0) {
    float2* ad = (float2*)&Ach[((size_t)b * 15 + tc) * 64];
    #pragma unroll
    for (int j = 0; j < 32; ++j) ad[j] = ap[j];
  }
}

// ---- S2: in-place chunk-state propagation: cst[t] <- h-state at end of t ---
__global__ __launch_bounds__(256)
void scan_comb(float* __restrict__ cst, const float* __restrict__ Ach) {
  int g = blockIdx.x * 256 + threadIdx.x;  // 0..262143
  int b = g >> 16;
  int rem = g & 65535;
  int d = rem >> 10;
  int m = rem & 1023;
  float h = 0.f;
  for (int t2 = 0; t2 < 15; ++t2) {
    size_t idx = (((size_t)(b * 15 + t2)) * 64 + d) * 1024 + m;
    h = fmaf(Ach[(b * 15 + t2) * 64 + d], h, cst[idx]);
    cst[idx] = h;
  }
}

// ---- S3: replay chunk from true initial state, emit y ----------------------
__global__ __launch_bounds__(256)
void scan_out(const float* __restrict__ u, const float* __restrict__ abc,
              const float* __restrict__ cst, const float* __restrict__ Dp,
              float* __restrict__ y) {
  __shared__ __align__(16) float sbuf[CL * 192];
  const int t = threadIdx.x, lane = t & 63, w = t >> 6;
  const int tc = blockIdx.x & 15;
  const int mg = (blockIdx.x >> 4) & 3;
  const int b  = blockIdx.x >> 6;
  const int r0 = b * 512 + tc * CL;

  const float4* src = (const float4*)(abc + (size_t)r0 * 192);
  #pragma unroll
  for (int i = 0; i < 6; ++i)
    ((float4*)sbuf)[t + i * 256] = src[t + i * 256];
  __syncthreads();

  const int m = (mg * 4 + w) * 64 + lane;
  const float* ub = u + (size_t)r0 * 1024 + m;
  float*       yb = y + (size_t)r0 * 1024 + m;
  const float dp = Dp[m];

  float2 h[32];
  if (tc == 0) {
    #pragma unroll
    for (int j = 0; j < 32; ++j) h[j] = make_float2(0.f, 0.f);
  } else {
    size_t cbase = (((size_t)b * 15 + (tc - 1)) * 64) * 1024 + m;
    #pragma unroll
    for (int j = 0; j < 32; ++j) {
      h[j].x = cst[cbase + (size_t)(2 * j)     * 1024];
      h[j].y = cst[cbase + (size_t)(2 * j + 1) * 1024];
    }
  }

  float u0 = ub[0];
  float u1 = ub[1024];
  for (int s = 0; s < CL; ++s) {
    int sn = (s < CL - 3) ? s + 2 : CL - 1;
    float u2 = ub[(size_t)sn * 1024];
    const float* L = sbuf + s * 192;
    float y0 = 0.f, y1 = 0.f, y2 = 0.f, y3 = 0.f;
    #pragma unroll
    for (int jj = 0; jj < 16; ++jj) {
      float4 a4 = *(const float4*)&L[4 * jj];
      float4 b4 = *(const float4*)&L[64 + 4 * jj];
      float4 c4 = *(const float4*)&L[128 + 4 * jj];
      h[2 * jj].x     = fmaf(h[2 * jj].x,     a4.x, b4.x * u0);
      h[2 * jj].y     = fmaf(h[2 * jj].y,     a4.y, b4.y * u0);
      h[2 * jj + 1].x = fmaf(h[2 * jj + 1].x, a4.z, b4.z * u0);
      h[2 * jj + 1].y = fmaf(h[2 * jj + 1].y, a4.w, b4.w * u0);
      y0 = fmaf(c4.x, h[2 * jj].x,     y0);
      y1 = fmaf(c4.y, h[2 * jj].y,     y1);
      y2 = fmaf(c4.z, h[2 * jj + 1].x, y2);
      y3 = fmaf(c4.w, h[2 * jj + 1].y, y3);
    }
    yb[(size_t)s * 1024] = (y0 + y1) + (y2 + y3) + u0 * dp;
    u0 = u1; u1 = u2;
  }
}

// ---------------- K4a: LayerNorm over 1024, write yn -------------------------
__global__ __launch_bounds__(256)
void k4a_ln(const float* __restrict__ y, const float* __restrict__ gamma,
            const float* __restrict__ beta, float* __restrict__ yn) {
  __shared__ float red[8];
  int t = threadIdx.x, lane = t & 63, wv = t >> 6;
  int row = blockIdx.x;
  float4 v = *(const float4*)&y[(size_t)row * 1024 + t * 4];
  float s1 = v.x + v.y + v.z + v.w;
  float s2 = v.x * v.x + v.y * v.y + v.z * v.z + v.w * v.w;
  #pragma unroll
  for (int o = 32; o; o >>= 1) {
    s1 += __shfl_xor(s1, o, 64);
    s2 += __shfl_xor(s2, o, 64);
  }
  if (lane == 0) { red[wv] = s1; red[4 + wv] = s2; }
  __syncthreads();
  float S1 = red[0] + red[1] + red[2] + red[3];
  float S2 = red[4] + red[5] + red[6] + red[7];
  float mean = S1 * (1.f / 1024.f);
  float var  = S2 * (1.f / 1024.f) - mean * mean;
  float rstd = rsqrtf(var + 1e-5f);
  float4 g  = *(const float4*)&gamma[t * 4];
  float4 be = *(const float4*)&beta[t * 4];
  float4 o;
  o.x = (v.x - mean) * rstd * g.x + be.x;
  o.y = (v.y - mean) * rstd * g.y + be.y;
  o.z = (v.z - mean) * rstd * g.z + be.z;
  o.w = (v.w - mean) * rstd * g.w + be.w;
  *(float4*)&yn[(size_t)row * 1024 + t * 4] = o;
}

// ---------------- K4c: reduce split-K partials + b_out -> out ----------------
__global__ __launch_bounds__(256)
void k4c_out(const float* __restrict__ part, const float* __restrict__ bout,
             float* __restrict__ out) {
  int g4 = blockIdx.x * 256 + threadIdx.x;
  size_t idx = (size_t)g4 * 4;
  const size_t PN = (size_t)ROWS * 128;
  float4 s = *(const float4*)&part[idx];
  #pragma unroll
  for (int z = 1; z < 4; ++z) {
    float4 p = *(const float4*)&part[z * PN + idx];
    s.x += p.x; s.y += p.y; s.z += p.z; s.w += p.w;
  }
  float4 bb = *(const float4*)&bout[idx & 127];
  s.x += bb.x; s.y += bb.y; s.z += bb.z; s.w += bb.w;
  *(float4*)&out[idx] = s;
}

extern "C" void kernel_launch(void* const* d_in, const int* in_sizes, int n_in,
                              void* d_out, int out_size, void* d_ws, size_t ws_size,
                              hipStream_t stream) {
  const float* x     = (const float*)d_in[0];
  const float* W_emb = (const float*)d_in[1];
  const float* b_emb = (const float*)d_in[2];
  const float* W_xp  = (const float*)d_in[3];
  const float* b_xp  = (const float*)d_in[4];
  const float* A     = (const float*)d_in[5];
  const float* Dp    = (const float*)d_in[6];
  const float* gamma = (const float*)d_in[7];
  const float* beta  = (const float*)d_in[8];
  const float* W_out = (const float*)d_in[9];
  const float* b_out = (const float*)d_in[10];
  float* out = (float*)d_out;
  float* ws  = (float*)d_ws;

  // ws layout (floats); total ~38.9 MB
  float* u    = ws;                 // 2,097,152  (reused as yn after scan)
  float* abc  = ws + 2097152;       //   393,216
  float* y    = ws + 2490368;       // 2,097,152
  float* wBC  = ws + 4587520;       //   131,072
  float* wd   = ws + 4718592;       //     1,024
  float* dr   = ws + 4719616;       //     2,048
  float* part = ws + 4721664;       // 1,048,576
  float* cst  = ws + 5770240;       // 3,932,160  (4*15*64*1024)
  float* Ach  = ws + 9702400;       //     3,840
  float* yn   = u;

  k0_rearrange<<<(1024 * 129 + 255) / 256, 256, 0, stream>>>(W_xp, wBC, wd);
  gemm_f32<false><<<dim3(16, 32, 1), 256, 0, stream>>>(x, W_emb, b_emb, u,
                                                       2048, 1024, 128, 0);
  k2d_gemv<<<512, 256, 0, stream>>>(u, wd, dr);
  gemm_f32<true><<<dim3(2, 32, 4), 256, 0, stream>>>(u, wBC, nullptr, part,
                                                     2048, 128, 1024, 256);
  k2e_epilogue<<<512, 256, 0, stream>>>(part, dr, b_xp, A, abc);
  // chunked scan
  scan_sum<<<240, 256, 0, stream>>>(u, abc, cst, Ach);
  scan_comb<<<1024, 256, 0, stream>>>(cst, Ach);
  scan_out<<<256, 256, 0, stream>>>(u, abc, cst, Dp, y);
  k4a_ln<<<2048, 256, 0, stream>>>(y, gamma, beta, yn);
  gemm_f32<true><<<dim3(2, 32, 4), 256, 0, stream>>>(yn, W_out, nullptr, part,
                                                     2048, 128, 1024, 256);
  k4c_out<<<256, 256, 0, stream>>>(part, b_out, out);
}

// Round 5
// 156.560 us; speedup vs baseline: 2.4722x; 1.1506x over previous
//
#include <hip/hip_runtime.h>
#include <cstddef>

typedef __attribute__((ext_vector_type(8))) short short8;
typedef __attribute__((ext_vector_type(4))) float f32x4;

// Dims (fixed by problem)
constexpr int ROWS = 2048;   // B*S
constexpr int CL   = 32;     // scan chunk length

__device__ inline ushort tobf(float f) {
  union { float f; unsigned u; } v; v.f = f;
  return (ushort)((v.u + 0x7FFFu + ((v.u >> 16) & 1u)) >> 16);
}

// ---------------- prep: weights -> bf16 [N][K] transposed, x -> bf16 ---------
__global__ __launch_bounds__(256)
void prep(const float* __restrict__ Wemb, const float* __restrict__ Wxp,
          const float* __restrict__ Wout, const float* __restrict__ x,
          ushort* __restrict__ WembT, ushort* __restrict__ wBCdT,
          ushort* __restrict__ WoutT, ushort* __restrict__ xbf) {
  int idx = blockIdx.x * 256 + threadIdx.x;
  if (idx < 131072) {                        // WembT[n][k] = Wemb[k][n] (K=128)
    int n = idx >> 7, k = idx & 127;
    WembT[idx] = tobf(Wemb[k * 1024 + n]);
  } else if (idx < 327680) {                 // wBCdT[n][k], n<128:B/C, 128:wd, else 0
    int j = idx - 131072;
    int n = j >> 10, k = j & 1023;
    float v = (n < 128) ? Wxp[k * 129 + 1 + n] : (n == 128 ? Wxp[k * 129] : 0.f);
    wBCdT[j] = tobf(v);
  } else if (idx < 458752) {                 // WoutT[n][k] = Wout[k][n] (K=1024)
    int j = idx - 327680;
    int n = j >> 10, k = j & 1023;
    WoutT[j] = tobf(Wout[k * 128 + n]);
  } else if (idx < 720896) {                 // x -> bf16
    int j = idx - 458752;
    xbf[j] = tobf(x[j]);
  }
}

// ---------------- bf16 MFMA GEMM: A[M][K] bf16, BT[N][K] bf16 ---------------
// Tile 64(M)x64(N), K-chunk 128 per block (blockIdx.z). 4 waves, each a 16-row
// strip x 64 cols. LDS XOR-swizzled (T2); NOTE: the XOR involution must be
// applied to the FULL final byte offset (rule #21) — (X^s)+c != (X+c)^s when
// c overlaps s's bits (the R2 bug: ks<<6 added after the XOR).
// SPLIT: C = part + z*M*N (fp32 partial). !SPLIT: C=u fp32 +bias, Cbf=u bf16.
template<bool SPLIT>
__global__ __launch_bounds__(256)
void gemm_bt_bf16(const ushort* __restrict__ A, const ushort* __restrict__ BT,
                  const float* __restrict__ bias, float* __restrict__ C,
                  ushort* __restrict__ Cbf, int M, int N, int K) {
  __shared__ __align__(16) ushort sA[8192];   // [64 rows][128 k] swizzled
  __shared__ __align__(16) ushort sB[8192];
  const int t  = threadIdx.x;
  const int n0 = blockIdx.x * 64;
  const int m0 = blockIdx.y * 64;
  const int kc = blockIdx.z << 7;

  #pragma unroll
  for (int i = 0; i < 4; ++i) {
    int c = t + (i << 8);
    int row = c >> 4, kk = (c & 15) << 3;
    float4 va = *(const float4*)(A  + (size_t)(m0 + row) * K + kc + kk);
    float4 vb = *(const float4*)(BT + (size_t)(n0 + row) * K + kc + kk);
    int byteoff = ((row << 8) + (kk << 1)) ^ ((row & 7) << 4);
    *(float4*)((char*)sA + byteoff) = va;
    *(float4*)((char*)sB + byteoff) = vb;
  }
  __syncthreads();

  const int lane = t & 63, w = t >> 6;
  const int wr = w << 4;                 // wave's m-strip base
  const int colsel = lane & 15;
  const int kg = lane >> 4;              // k-group (8 k's each)

  short8 a[4];
  {
    int arow = wr + colsel;
    int lin = (arow << 8) + (kg << 4);
    int swz = (arow & 7) << 4;
    #pragma unroll
    for (int ks = 0; ks < 4; ++ks)
      a[ks] = *(const short8*)((const char*)sA + ((lin + (ks << 6)) ^ swz));
  }

  f32x4 acc[4];
  #pragma unroll
  for (int nf = 0; nf < 4; ++nf) acc[nf] = (f32x4)(0.f);

  #pragma unroll
  for (int nf = 0; nf < 4; ++nf) {
    int brow = (nf << 4) + colsel;
    int lin = (brow << 8) + (kg << 4);
    int swz = (brow & 7) << 4;
    #pragma unroll
    for (int ks = 0; ks < 4; ++ks) {
      short8 b = *(const short8*)((const char*)sB + ((lin + (ks << 6)) ^ swz));
      acc[nf] = __builtin_amdgcn_mfma_f32_16x16x32_bf16(a[ks], b, acc[nf], 0, 0, 0);
    }
  }

  // epilogue: D layout col=lane&15, row=(lane>>4)*4+reg  [m89]
  const int r4 = kg << 2;
  float* Cp = C;
  if (SPLIT) Cp += (size_t)blockIdx.z * (size_t)M * N;
  #pragma unroll
  for (int nf = 0; nf < 4; ++nf) {
    int gn = n0 + (nf << 4) + colsel;
    #pragma unroll
    for (int reg = 0; reg < 4; ++reg) {
      int gm = m0 + wr + r4 + reg;
      if (SPLIT) {
        Cp[(size_t)gm * N + gn] = acc[nf][reg];
      } else {
        float v = acc[nf][reg] + bias[gn];
        C[(size_t)gm * N + gn] = v;
        Cbf[(size_t)gm * N + gn] = tobf(v);
      }
    }
  }
}

// ---------------- K2e: reduce split-K partials + build abc -------------------
// part: [8][2048][192]; col 128 = delta_raw. abc[row][0:64]=A_bar,[64:128]=B_bar,[128:192]=C
__global__ __launch_bounds__(256)
void k2e_epilogue(const float* __restrict__ part, const float* __restrict__ bxp,
                  const float* __restrict__ A, float* __restrict__ abc) {
  int gid = blockIdx.x * 256 + threadIdx.x;  // 0..131071
  int row = gid >> 6, d = gid & 63;
  const size_t PN = (size_t)ROWS * 192;
  float sb = 0.f, sc = 0.f, dr = 0.f;
  #pragma unroll
  for (int z = 0; z < 8; ++z) {
    const float* p = part + z * PN + (size_t)row * 192;
    sb += p[d];
    sc += p[64 + d];
    dr += p[128];
  }
  sb += bxp[1 + d];
  sc += bxp[65 + d];
  float xv = dr + bxp[0];
  float sp = (xv > 15.f) ? xv : log1pf(__expf(xv));
  float delta = 0.01f * sp;
  float* o = abc + (size_t)row * 192;
  o[d]       = __expf(delta * A[d]);
  o[64 + d]  = delta * sb;
  o[128 + d] = sc;
}

// ============================================================================
// Chunked scan (3 phases). lane = m, all 64 d in registers. No cross-lane ops.
// cst: [b][tc<15][d][1024m] ; Ach: [b][tc<15][d]
// ============================================================================
__global__ __launch_bounds__(256)
void scan_sum(const float* __restrict__ u, const float* __restrict__ abc,
              float* __restrict__ cst, float* __restrict__ Ach) {
  __shared__ __align__(16) float sbuf[CL * 192];
  const int t = threadIdx.x, lane = t & 63, w = t >> 6;
  const int tc = blockIdx.x % 15;
  const int mg = (blockIdx.x / 15) & 3;
  const int b  = blockIdx.x / 60;
  const int r0 = b * 512 + tc * CL;

  const float4* src = (const float4*)(abc + (size_t)r0 * 192);
  #pragma unroll
  for (int i = 0; i < 6; ++i)
    ((float4*)sbuf)[t + i * 256] = src[t + i * 256];
  __syncthreads();

  const int m = (mg * 4 + w) * 64 + lane;
  const float* ub = u + (size_t)r0 * 1024 + m;
  const bool doAp = (mg == 0 && w == 0);

  float2 h[32];
  float2 ap[32];
  #pragma unroll
  for (int j = 0; j < 32; ++j) { h[j] = make_float2(0.f, 0.f); ap[j] = make_float2(1.f, 1.f); }

  float u0 = ub[0];
  float u1 = ub[1024];
  for (int s = 0; s < CL; ++s) {
    int sn = (s < CL - 3) ? s + 2 : CL - 1;
    float u2 = ub[(size_t)sn * 1024];
    const float* L = sbuf + s * 192;
    #pragma unroll
    for (int jj = 0; jj < 16; ++jj) {
      float4 a4 = *(const float4*)&L[4 * jj];
      float4 b4 = *(const float4*)&L[64 + 4 * jj];
      h[2 * jj].x     = fmaf(h[2 * jj].x,     a4.x, b4.x * u0);
      h[2 * jj].y     = fmaf(h[2 * jj].y,     a4.y, b4.y * u0);
      h[2 * jj + 1].x = fmaf(h[2 * jj + 1].x, a4.z, b4.z * u0);
      h[2 * jj + 1].y = fmaf(h[2 * jj + 1].y, a4.w, b4.w * u0);
    }
    if (doAp) {
      #pragma unroll
      for (int jj = 0; jj < 16; ++jj) {
        float4 a4 = *(const float4*)&L[4 * jj];
        ap[2 * jj].x     *= a4.x;
        ap[2 * jj].y     *= a4.y;
        ap[2 * jj + 1].x *= a4.z;
        ap[2 * jj + 1].y *= a4.w;
      }
    }
    u0 = u1; u1 = u2;
  }

  size_t cbase = (((size_t)b * 15 + tc) * 64) * 1024 + m;
  #pragma unroll
  for (int j = 0; j < 32; ++j) {
    cst[cbase + (size_t)(2 * j)     * 1024] = h[j].x;
    cst[cbase + (size_t)(2 * j + 1) * 1024] = h[j].y;
  }
  if (doAp && lane == 0) {
    float2* ad = (float2*)&Ach[((size_t)b * 15 + tc) * 64];
    #pragma unroll
    for (int j = 0; j < 32; ++j) ad[j] = ap[j];
  }
}

__global__ __launch_bounds__(256)
void scan_comb(float* __restrict__ cst, const float* __restrict__ Ach) {
  int g = blockIdx.x * 256 + threadIdx.x;  // 0..262143
  int b = g >> 16;
  int rem = g & 65535;
  int d = rem >> 10;
  int m = rem & 1023;
  float h = 0.f;
  for (int t2 = 0; t2 < 15; ++t2) {
    size_t idx = (((size_t)(b * 15 + t2)) * 64 + d) * 1024 + m;
    h = fmaf(Ach[(b * 15 + t2) * 64 + d], h, cst[idx]);
    cst[idx] = h;
  }
}

__global__ __launch_bounds__(256)
void scan_out(const float* __restrict__ u, const float* __restrict__ abc,
              const float* __restrict__ cst, const float* __restrict__ Dp,
              float* __restrict__ y) {
  __shared__ __align__(16) float sbuf[CL * 192];
  const int t = threadIdx.x, lane = t & 63, w = t >> 6;
  const int tc = blockIdx.x & 15;
  const int mg = (blockIdx.x >> 4) & 3;
  const int b  = blockIdx.x >> 6;
  const int r0 = b * 512 + tc * CL;

  const float4* src = (const float4*)(abc + (size_t)r0 * 192);
  #pragma unroll
  for (int i = 0; i < 6; ++i)
    ((float4*)sbuf)[t + i * 256] = src[t + i * 256];
  __syncthreads();

  const int m = (mg * 4 + w) * 64 + lane;
  const float* ub = u + (size_t)r0 * 1024 + m;
  float*       yb = y + (size_t)r0 * 1024 + m;
  const float dp = Dp[m];

  float2 h[32];
  if (tc == 0) {
    #pragma unroll
    for (int j = 0; j < 32; ++j) h[j] = make_float2(0.f, 0.f);
  } else {
    size_t cbase = (((size_t)b * 15 + (tc - 1)) * 64) * 1024 + m;
    #pragma unroll
    for (int j = 0; j < 32; ++j) {
      h[j].x = cst[cbase + (size_t)(2 * j)     * 1024];
      h[j].y = cst[cbase + (size_t)(2 * j + 1) * 1024];
    }
  }

  float u0 = ub[0];
  float u1 = ub[1024];
  for (int s = 0; s < CL; ++s) {
    int sn = (s < CL - 3) ? s + 2 : CL - 1;
    float u2 = ub[(size_t)sn * 1024];
    const float* L = sbuf + s * 192;
    float y0 = 0.f, y1 = 0.f, y2 = 0.f, y3 = 0.f;
    #pragma unroll
    for (int jj = 0; jj < 16; ++jj) {
      float4 a4 = *(const float4*)&L[4 * jj];
      float4 b4 = *(const float4*)&L[64 + 4 * jj];
      float4 c4 = *(const float4*)&L[128 + 4 * jj];
      h[2 * jj].x     = fmaf(h[2 * jj].x,     a4.x, b4.x * u0);
      h[2 * jj].y     = fmaf(h[2 * jj].y,     a4.y, b4.y * u0);
      h[2 * jj + 1].x = fmaf(h[2 * jj + 1].x, a4.z, b4.z * u0);
      h[2 * jj + 1].y = fmaf(h[2 * jj + 1].y, a4.w, b4.w * u0);
      y0 = fmaf(c4.x, h[2 * jj].x,     y0);
      y1 = fmaf(c4.y, h[2 * jj].y,     y1);
      y2 = fmaf(c4.z, h[2 * jj + 1].x, y2);
      y3 = fmaf(c4.w, h[2 * jj + 1].y, y3);
    }
    yb[(size_t)s * 1024] = (y0 + y1) + (y2 + y3) + u0 * dp;
    u0 = u1; u1 = u2;
  }
}

// ---------------- K4a: LayerNorm over 1024 -> yn (bf16 direct) ---------------
__global__ __launch_bounds__(256)
void k4a_ln(const float* __restrict__ y, const float* __restrict__ gamma,
            const float* __restrict__ beta, ushort* __restrict__ ynbf) {
  __shared__ float red[8];
  int t = threadIdx.x, lane = t & 63, wv = t >> 6;
  int row = blockIdx.x;
  float4 v = *(const float4*)&y[(size_t)row * 1024 + t * 4];
  float s1 = v.x + v.y + v.z + v.w;
  float s2 = v.x * v.x + v.y * v.y + v.z * v.z + v.w * v.w;
  #pragma unroll
  for (int o = 32; o; o >>= 1) {
    s1 += __shfl_xor(s1, o, 64);
    s2 += __shfl_xor(s2, o, 64);
  }
  if (lane == 0) { red[wv] = s1; red[4 + wv] = s2; }
  __syncthreads();
  float S1 = red[0] + red[1] + red[2] + red[3];
  float S2 = red[4] + red[5] + red[6] + red[7];
  float mean = S1 * (1.f / 1024.f);
  float var  = S2 * (1.f / 1024.f) - mean * mean;
  float rstd = rsqrtf(var + 1e-5f);
  float4 g  = *(const float4*)&gamma[t * 4];
  float4 be = *(const float4*)&beta[t * 4];
  ushort4 o;
  o.x = tobf((v.x - mean) * rstd * g.x + be.x);
  o.y = tobf((v.y - mean) * rstd * g.y + be.y);
  o.z = tobf((v.z - mean) * rstd * g.z + be.z);
  o.w = tobf((v.w - mean) * rstd * g.w + be.w);
  *(ushort4*)&ynbf[(size_t)row * 1024 + t * 4] = o;
}

// ---------------- K4c: reduce split-K partials + b_out -> out ----------------
__global__ __launch_bounds__(256)
void k4c_out(const float* __restrict__ part, const float* __restrict__ bout,
             float* __restrict__ out) {
  int g4 = blockIdx.x * 256 + threadIdx.x;
  size_t idx = (size_t)g4 * 4;
  const size_t PN = (size_t)ROWS * 128;
  float4 s = *(const float4*)&part[idx];
  #pragma unroll
  for (int z = 1; z < 8; ++z) {
    float4 p = *(const float4*)&part[z * PN + idx];
    s.x += p.x; s.y += p.y; s.z += p.z; s.w += p.w;
  }
  float4 bb = *(const float4*)&bout[idx & 127];
  s.x += bb.x; s.y += bb.y; s.z += bb.z; s.w += bb.w;
  *(float4*)&out[idx] = s;
}

extern "C" void kernel_launch(void* const* d_in, const int* in_sizes, int n_in,
                              void* d_out, int out_size, void* d_ws, size_t ws_size,
                              hipStream_t stream) {
  const float* x     = (const float*)d_in[0];
  const float* W_emb = (const float*)d_in[1];
  const float* b_emb = (const float*)d_in[2];
  const float* W_xp  = (const float*)d_in[3];
  const float* b_xp  = (const float*)d_in[4];
  const float* A     = (const float*)d_in[5];
  const float* Dp    = (const float*)d_in[6];
  const float* gamma = (const float*)d_in[7];
  const float* beta  = (const float*)d_in[8];
  const float* W_out = (const float*)d_in[9];
  const float* b_out = (const float*)d_in[10];
  float* out = (float*)d_out;
  float* ws  = (float*)d_ws;

  // ws layout
  float* u    = ws;                         // 2,097,152 f
  float* y    = u + 2097152;                // 2,097,152 f
  float* abc  = y + 2097152;                //   393,216 f
  float* part = abc + 393216;               // 3,145,728 f (8*2048*192 max)
  float* cst  = part + 3145728;             // 3,932,160 f
  float* Ach  = cst + 3932160;              //     4,096 f (3840 used)
  ushort* ubf   = (ushort*)(Ach + 4096);    // 2,097,152 us
  ushort* ynbf  = ubf + 2097152;            // 2,097,152 us
  ushort* xbf   = ynbf + 2097152;           //   262,144 us
  ushort* WembT = xbf + 262144;             //   131,072 us
  ushort* wBCdT = WembT + 131072;           //   196,608 us
  ushort* WoutT = wBCdT + 196608;           //   131,072 us

  // prep: weight transposes -> bf16, x -> bf16
  prep<<<2816, 256, 0, stream>>>(W_emb, W_xp, W_out, x, WembT, wBCdT, WoutT, xbf);
  // G1: u = x @ W_emb + b_emb  (M=2048,N=1024,K=128), writes u fp32 + bf16
  gemm_bt_bf16<false><<<dim3(16, 32, 1), 256, 0, stream>>>(
      xbf, WembT, b_emb, u, ubf, 2048, 1024, 128);
  // G2: sel partials (M=2048,N=192,K=1024, split-K=8); col 128 = delta GEMV
  gemm_bt_bf16<true><<<dim3(3, 32, 8), 256, 0, stream>>>(
      ubf, wBCdT, nullptr, part, nullptr, 2048, 192, 1024);
  // epilogue: reduce + bias + softplus -> abc
  k2e_epilogue<<<512, 256, 0, stream>>>(part, b_xp, A, abc);
  // chunked scan
  scan_sum<<<240, 256, 0, stream>>>(u, abc, cst, Ach);
  scan_comb<<<1024, 256, 0, stream>>>(cst, Ach);
  scan_out<<<256, 256, 0, stream>>>(u, abc, cst, Dp, y);
  // LayerNorm -> yn bf16
  k4a_ln<<<2048, 256, 0, stream>>>(y, gamma, beta, ynbf);
  // G4: out partials (M=2048,N=128,K=1024, split-K=8)
  gemm_bt_bf16<true><<<dim3(2, 32, 8), 256, 0, stream>>>(
      ynbf, WoutT, nullptr, part, nullptr, 2048, 128, 1024);
  // reduce + b_out
  k4c_out<<<256, 256, 0, stream>>>(part, b_out, out);
}